// Round 1
// baseline (1445.372 us; speedup 1.0000x reference)
//
#include <hip/hip_runtime.h>
#include <stdint.h>

typedef unsigned short u16;
typedef __bf16 bf16x8 __attribute__((ext_vector_type(8)));
typedef unsigned short u16x8 __attribute__((ext_vector_type(8)));
typedef unsigned short u16x4 __attribute__((ext_vector_type(4)));
typedef float f32x4 __attribute__((ext_vector_type(4)));

#define B_ 2
#define S_ 2048
#define HID_ 4096
#define NH_ 32
#define NKV_ 8
#define HD_ 128
#define NTOT_ 6144  // NH*HD + 2*NKV*HD
#define SCALE_ 0.08838834764831845f

// ---------- bf16 helpers (raw u16 storage; no hip_bf16.h dependency) ----------
__device__ __forceinline__ u16 f2b(float f) {
  union { float f; uint32_t u; } v; v.f = f;
  uint32_t u = v.u;
  u = u + 0x7fffu + ((u >> 16) & 1u);   // round-to-nearest-even
  return (u16)(u >> 16);
}
__device__ __forceinline__ float b2f(u16 s) {
  union { uint32_t u; float f; } v; v.u = ((uint32_t)s) << 16;
  return v.f;
}
__device__ __forceinline__ bf16x8 ldb8(const u16* p) {
  u16x8 u = *(const u16x8*)p;
  return __builtin_bit_cast(bf16x8, u);
}

// ---------- kernel 1: f32 -> bf16 (vectorized) ----------
__global__ __launch_bounds__(256) void k_convx(const float* __restrict__ src,
                                               u16* __restrict__ dst, int n4) {
  int i = blockIdx.x * 256 + threadIdx.x;
  if (i >= n4) return;
  const float4 v = ((const float4*)src)[i];
  u16x4 o = { f2b(v.x), f2b(v.y), f2b(v.z), f2b(v.w) };
  *(u16x4*)(dst + (size_t)i * 4) = o;
}

// ---------- kernel 2: transpose-convert W f32 [Kd][N] -> bf16 [N][Kd] ----------
__global__ __launch_bounds__(256) void k_convT(const float* __restrict__ src,
                                               u16* __restrict__ dst, int N, int Kd) {
  __shared__ u16 tile[64][65];
  int k0 = blockIdx.x * 64, n0 = blockIdx.y * 64;
  int t = threadIdx.x;
  int rr = t >> 4;          // 0..15
  int cc = (t & 15) * 4;    // 0..60
#pragma unroll
  for (int p = 0; p < 4; ++p) {
    int r = p * 16 + rr;    // k row within tile
    float4 v = *(const float4*)&src[(size_t)(k0 + r) * N + n0 + cc];
    tile[cc + 0][r] = f2b(v.x);
    tile[cc + 1][r] = f2b(v.y);
    tile[cc + 2][r] = f2b(v.z);
    tile[cc + 3][r] = f2b(v.w);
  }
  __syncthreads();
#pragma unroll
  for (int p = 0; p < 4; ++p) {
    int n = p * 16 + rr;    // n row within tile
    u16x4 o = { tile[n][cc], tile[n][cc + 1], tile[n][cc + 2], tile[n][cc + 3] };
    *(u16x4*)&dst[(size_t)(n0 + n) * Kd + k0 + cc] = o;
  }
}

// ---------- kernel 3: bf16 GEMM, 128x128 tile, 4 waves, 16x16x32 MFMA ----------
// A: [M][Kd] bf16 row-major. Bt: [N][Kd] bf16 (i.e. B transposed).
// MODE 0: QKV epilogue (scatter to Q[b,h,s,d], K[b,kv,s,d], V^T[b,kv,d,s], bf16)
// MODE 1: f32 C output [M][N]
template <int MODE>
__global__ __launch_bounds__(256) void k_gemm(const u16* __restrict__ A,
                                              const u16* __restrict__ Bt,
                                              float* __restrict__ Cf,
                                              u16* __restrict__ Qb,
                                              u16* __restrict__ Kb,
                                              u16* __restrict__ Vb,
                                              int M, int N, int Kd) {
  __shared__ __align__(16) u16 As[128][32];
  __shared__ __align__(16) u16 Bs[128][32];
  int m0 = blockIdx.y * 128, n0 = blockIdx.x * 128;
  int t = threadIdx.x, lane = t & 63, wave = t >> 6;
  int wr = wave >> 1, wc = wave & 1;     // 2x2 wave grid; wave tile 64x64
  int lg = lane >> 4, l16 = lane & 15;
  f32x4 acc[4][4] = {};

  for (int k0 = 0; k0 < Kd; k0 += 32) {
    __syncthreads();
#pragma unroll
    for (int p = 0; p < 2; ++p) {
      int idx = p * 256 + t;
      int r = idx >> 2, o = (idx & 3) * 8;      // 16B per thread per pass
      *(u16x8*)&As[r][o] = *(const u16x8*)&A[(size_t)(m0 + r) * Kd + k0 + o];
      *(u16x8*)&Bs[r][o] = *(const u16x8*)&Bt[(size_t)(n0 + r) * Kd + k0 + o];
    }
    __syncthreads();
    bf16x8 af[4], bfr[4];
#pragma unroll
    for (int i = 0; i < 4; ++i) {
      af[i]  = ldb8(&As[wr * 64 + i * 16 + l16][lg * 8]);
      bfr[i] = ldb8(&Bs[wc * 64 + i * 16 + l16][lg * 8]);
    }
#pragma unroll
    for (int i = 0; i < 4; ++i)
#pragma unroll
      for (int j = 0; j < 4; ++j)
        acc[i][j] = __builtin_amdgcn_mfma_f32_16x16x32_bf16(af[i], bfr[j], acc[i][j], 0, 0, 0);
  }

  if (MODE == 1) {
#pragma unroll
    for (int i = 0; i < 4; ++i)
#pragma unroll
      for (int j = 0; j < 4; ++j)
#pragma unroll
        for (int r = 0; r < 4; ++r) {
          int m = m0 + wr * 64 + i * 16 + lg * 4 + r;
          int n = n0 + wc * 64 + j * 16 + l16;
          Cf[(size_t)m * N + n] = acc[i][j][r];
        }
  } else {
    int head = n0 >> 7;                 // BN=128 == HD -> one head per block (uniform)
#pragma unroll
    for (int i = 0; i < 4; ++i)
#pragma unroll
      for (int j = 0; j < 4; ++j)
#pragma unroll
        for (int r = 0; r < 4; ++r) {
          int m = m0 + wr * 64 + i * 16 + lg * 4 + r;
          int d = wc * 64 + j * 16 + l16;       // dim within head
          int b = m >> 11, s = m & (S_ - 1);
          u16 val = f2b(acc[i][j][r]);
          if (head < NH_) {
            Qb[(((size_t)b * NH_ + head) * S_ + s) * HD_ + d] = val;
          } else if (head < NH_ + NKV_) {
            Kb[(((size_t)b * NKV_ + (head - NH_)) * S_ + s) * HD_ + d] = val;
          } else {
            // V stored transposed: Vt[b][kv][d][s]
            Vb[(((size_t)b * NKV_ + (head - NH_ - NKV_)) * HD_ + d) * S_ + s] = val;
          }
        }
  }
}

// ---------- kernel 4: RoPE in-place on [rows][128] bf16, one wave per row ----------
__global__ __launch_bounds__(256) void k_rope(u16* __restrict__ buf, const int* __restrict__ pos,
                                              const float* __restrict__ ct, const float* __restrict__ st,
                                              int H, int rows) {
  int wave = threadIdx.x >> 6, lane = threadIdx.x & 63;
  int row = blockIdx.x * 4 + wave;
  if (row >= rows) return;
  int s = row & (S_ - 1);
  int b = row / (H * S_);
  int p = pos[b * S_ + s];
  size_t base = (size_t)row * HD_;
  float x1 = b2f(buf[base + lane]);
  float x2 = b2f(buf[base + 64 + lane]);
  float c  = ct[(size_t)p * HD_ + lane];    // cos[p][d] == cos[p][d+64] (table duplicated)
  float sn = st[(size_t)p * HD_ + lane];
  buf[base + lane]      = f2b(x1 * c - x2 * sn);
  buf[base + 64 + lane] = f2b(x2 * c + x1 * sn);
}

// ---------- kernel 5: causal GQA flash attention ----------
// Q [b,h,s,d], K [b,kv,s,d], Vt [b,kv,d,s] bf16 -> Ob [b,s,h*128+d] bf16
__global__ __launch_bounds__(256) void k_attn(const u16* __restrict__ Q, const u16* __restrict__ K,
                                              const u16* __restrict__ Vt, u16* __restrict__ Ob) {
  int bid = blockIdx.x;
  int qt = bid & 31;             // S/64
  int h  = (bid >> 5) & 31;
  int b  = bid >> 10;
  int kvh = h >> 2;              // NH/NKV = 4
  int wave = threadIdx.x >> 6, lane = threadIdx.x & 63;
  int lg = lane >> 4, l16 = lane & 15;

  const u16* Qp = Q  + (((size_t)b * NH_  + h)   * S_) * HD_;
  const u16* Kp = K  + (((size_t)b * NKV_ + kvh) * S_) * HD_;
  const u16* Vp = Vt + (((size_t)b * NKV_ + kvh) * HD_) * S_;

  int q0 = qt * 64 + wave * 16;            // this wave's 16 q rows
  int qrow = q0 + l16;

  bf16x8 qf[4];
#pragma unroll
  for (int c = 0; c < 4; ++c)
    qf[c] = ldb8(&Qp[(size_t)qrow * HD_ + c * 32 + lg * 8]);

  f32x4 oacc[8] = {};
  float m_r[4], l_r[4];
#pragma unroll
  for (int r = 0; r < 4; ++r) { m_r[r] = -1e30f; l_r[r] = 0.f; }

  __shared__ __align__(16) u16 plds[4][16][32];

  int ntiles = (q0 + 47) / 32;             // covers keys <= q0+15
  for (int tI = 0; tI < ntiles; ++tI) {
    int kb = tI * 32;
    f32x4 s0 = {0.f, 0.f, 0.f, 0.f};
    f32x4 s1 = {0.f, 0.f, 0.f, 0.f};
#pragma unroll
    for (int c = 0; c < 4; ++c) {
      bf16x8 kf0 = ldb8(&Kp[(size_t)(kb + l16)      * HD_ + c * 32 + lg * 8]);
      bf16x8 kf1 = ldb8(&Kp[(size_t)(kb + 16 + l16) * HD_ + c * 32 + lg * 8]);
      s0 = __builtin_amdgcn_mfma_f32_16x16x32_bf16(qf[c], kf0, s0, 0, 0, 0);
      s1 = __builtin_amdgcn_mfma_f32_16x16x32_bf16(qf[c], kf1, s1, 0, 0, 0);
    }
    int key0 = kb + l16, key1 = kb + 16 + l16;
    float p0[4], p1[4];
#pragma unroll
    for (int r = 0; r < 4; ++r) {
      int qr = q0 + lg * 4 + r;
      float v0 = (key0 <= qr) ? s0[r] * SCALE_ : -1e30f;
      float v1 = (key1 <= qr) ? s1[r] * SCALE_ : -1e30f;
      float mx = fmaxf(v0, v1);
#pragma unroll
      for (int off = 8; off >= 1; off >>= 1) mx = fmaxf(mx, __shfl_xor(mx, off));
      float mnew = fmaxf(m_r[r], mx);
      float alpha = __expf(m_r[r] - mnew);
      p0[r] = __expf(v0 - mnew);
      p1[r] = __expf(v1 - mnew);
      float rs = p0[r] + p1[r];
#pragma unroll
      for (int off = 8; off >= 1; off >>= 1) rs += __shfl_xor(rs, off);
      l_r[r] = l_r[r] * alpha + rs;
      m_r[r] = mnew;
#pragma unroll
      for (int ns = 0; ns < 8; ++ns) oacc[ns][r] *= alpha;
    }
#pragma unroll
    for (int r = 0; r < 4; ++r) {
      plds[wave][lg * 4 + r][l16]      = f2b(p0[r]);
      plds[wave][lg * 4 + r][l16 + 16] = f2b(p1[r]);
    }
    // within-wave LDS dependency; compiler inserts lgkmcnt wait
    bf16x8 pf = ldb8(&plds[wave][l16][lg * 8]);
#pragma unroll
    for (int ns = 0; ns < 8; ++ns) {
      bf16x8 vf = ldb8(&Vp[(size_t)(ns * 16 + l16) * S_ + kb + lg * 8]);
      oacc[ns] = __builtin_amdgcn_mfma_f32_16x16x32_bf16(pf, vf, oacc[ns], 0, 0, 0);
    }
  }

#pragma unroll
  for (int r = 0; r < 4; ++r) l_r[r] = 1.0f / l_r[r];
#pragma unroll
  for (int ns = 0; ns < 8; ++ns)
#pragma unroll
    for (int r = 0; r < 4; ++r) {
      int qout = q0 + lg * 4 + r;
      Ob[((size_t)b * S_ + qout) * (NH_ * HD_) + h * HD_ + ns * 16 + l16] =
          f2b(oacc[ns][r] * l_r[r]);
    }
}

// ---------- launch ----------
extern "C" void kernel_launch(void* const* d_in, const int* in_sizes, int n_in,
                              void* d_out, int out_size, void* d_ws, size_t ws_size,
                              hipStream_t stream) {
  const float* hs  = (const float*)d_in[0];
  const int*   pos = (const int*)d_in[1];
  const float* ct  = (const float*)d_in[2];
  const float* st  = (const float*)d_in[3];
  const float* Wq  = (const float*)d_in[4];
  const float* Wk  = (const float*)d_in[5];
  const float* Wv  = (const float*)d_in[6];
  const float* Wo  = (const float*)d_in[7];
  float* out = (float*)d_out;

  char* w = (char*)d_ws;
  u16* Xb    = (u16*)(w);                       // 33,554,432 B  [4096][4096]
  u16* WqkvT = (u16*)(w + 33554432ull);         // 50,331,648 B  [6144][4096]
  u16* WoT   = (u16*)(w + 83886080ull);         // 33,554,432 B  [4096][4096]
  u16* Qb    = (u16*)(w + 117440512ull);        // 33,554,432 B  [2][32][2048][128]
  u16* Kb    = (u16*)(w + 150994944ull);        //  8,388,608 B  [2][8][2048][128]
  u16* Vb    = (u16*)(w + 159383552ull);        //  8,388,608 B  [2][8][128][2048]
  u16* Attb  = (u16*)(w + 167772160ull);        // 33,554,432 B  [4096][4096]

  // 1. hidden -> bf16
  k_convx<<<16384, 256, 0, stream>>>(hs, Xb, 4194304);
  // 2. weights -> transposed bf16 (Wq|Wk|Wv concatenated as rows of WqkvT)
  k_convT<<<dim3(64, 64), 256, 0, stream>>>(Wq, WqkvT, 4096, 4096);
  k_convT<<<dim3(64, 16), 256, 0, stream>>>(Wk, WqkvT + (size_t)4096 * 4096, 1024, 4096);
  k_convT<<<dim3(64, 16), 256, 0, stream>>>(Wv, WqkvT + (size_t)5120 * 4096, 1024, 4096);
  k_convT<<<dim3(64, 64), 256, 0, stream>>>(Wo, WoT, 4096, 4096);
  // 3. QKV projection
  k_gemm<0><<<dim3(48, 32), 256, 0, stream>>>(Xb, WqkvT, nullptr, Qb, Kb, Vb, 4096, NTOT_, 4096);
  // 4. RoPE (Q then K)
  k_rope<<<32768, 256, 0, stream>>>(Qb, pos, ct, st, NH_, B_ * NH_ * S_);
  k_rope<<<8192, 256, 0, stream>>>(Kb, pos, ct, st, NKV_, B_ * NKV_ * S_);
  // 5. causal GQA flash attention
  k_attn<<<2048, 256, 0, stream>>>(Qb, Kb, Vb, Attb);
  // 6. output projection (f32 out)
  k_gemm<1><<<dim3(32, 32), 256, 0, stream>>>(Attb, WoT, out, nullptr, nullptr, nullptr, 4096, 4096, 4096);
}

// Round 2
// 731.752 us; speedup vs baseline: 1.9752x; 1.9752x over previous
//
#include <hip/hip_runtime.h>
#include <stdint.h>

typedef unsigned short u16;
typedef __bf16 bf16x8 __attribute__((ext_vector_type(8)));
typedef unsigned short u16x8 __attribute__((ext_vector_type(8)));
typedef unsigned short u16x4 __attribute__((ext_vector_type(4)));
typedef float f32x4 __attribute__((ext_vector_type(4)));

#define B_ 2
#define S_ 2048
#define HID_ 4096
#define NH_ 32
#define NKV_ 8
#define HD_ 128
#define NTOT_ 6144  // NH*HD + 2*NKV*HD
#define SCALE_ 0.08838834764831845f

// ---------- bf16 helpers ----------
__device__ __forceinline__ u16 f2b(float f) {
  union { float f; uint32_t u; } v; v.f = f;
  uint32_t u = v.u;
  u = u + 0x7fffu + ((u >> 16) & 1u);   // round-to-nearest-even
  return (u16)(u >> 16);
}
__device__ __forceinline__ float b2f(u16 s) {
  union { uint32_t u; float f; } v; v.u = ((uint32_t)s) << 16;
  return v.f;
}
__device__ __forceinline__ bf16x8 ldb8(const u16* p) {
  u16x8 u = *(const u16x8*)p;
  return __builtin_bit_cast(bf16x8, u);
}
__device__ __forceinline__ bf16x8 ldb8b(const char* p) {
  u16x8 u = *(const u16x8*)p;
  return __builtin_bit_cast(bf16x8, u);
}

// ---------- kernel 1: f32 -> bf16 (vectorized) ----------
__global__ __launch_bounds__(256) void k_convx(const float* __restrict__ src,
                                               u16* __restrict__ dst, int n4) {
  int i = blockIdx.x * 256 + threadIdx.x;
  if (i >= n4) return;
  const float4 v = ((const float4*)src)[i];
  u16x4 o = { f2b(v.x), f2b(v.y), f2b(v.z), f2b(v.w) };
  *(u16x4*)(dst + (size_t)i * 4) = o;
}

// ---------- kernel 2: transpose-convert W f32 [Kd][N] -> bf16 [N][Kd] ----------
__global__ __launch_bounds__(256) void k_convT(const float* __restrict__ src,
                                               u16* __restrict__ dst, int N, int Kd) {
  __shared__ u16 tile[64][65];
  int k0 = blockIdx.x * 64, n0 = blockIdx.y * 64;
  int t = threadIdx.x;
  int rr = t >> 4;          // 0..15
  int cc = (t & 15) * 4;    // 0..60
#pragma unroll
  for (int p = 0; p < 4; ++p) {
    int r = p * 16 + rr;
    float4 v = *(const float4*)&src[(size_t)(k0 + r) * N + n0 + cc];
    tile[cc + 0][r] = f2b(v.x);
    tile[cc + 1][r] = f2b(v.y);
    tile[cc + 2][r] = f2b(v.z);
    tile[cc + 3][r] = f2b(v.w);
  }
  __syncthreads();
#pragma unroll
  for (int p = 0; p < 4; ++p) {
    int n = p * 16 + rr;
    u16x4 o = { tile[n][cc], tile[n][cc + 1], tile[n][cc + 2], tile[n][cc + 3] };
    *(u16x4*)&dst[(size_t)(n0 + n) * Kd + k0 + cc] = o;
  }
}

// ---------- kernel 3: bf16 GEMM, 128x128 tile, 4 waves, 16x16x32 MFMA ----------
template <int MODE>
__global__ __launch_bounds__(256) void k_gemm(const u16* __restrict__ A,
                                              const u16* __restrict__ Bt,
                                              float* __restrict__ Cf,
                                              u16* __restrict__ Qb,
                                              u16* __restrict__ Kb,
                                              u16* __restrict__ Vb,
                                              int M, int N, int Kd) {
  __shared__ __align__(16) u16 As[128][32];
  __shared__ __align__(16) u16 Bs[128][32];
  int m0 = blockIdx.y * 128, n0 = blockIdx.x * 128;
  int t = threadIdx.x, lane = t & 63, wave = t >> 6;
  int wr = wave >> 1, wc = wave & 1;
  int lg = lane >> 4, l16 = lane & 15;
  f32x4 acc[4][4] = {};

  for (int k0 = 0; k0 < Kd; k0 += 32) {
    __syncthreads();
#pragma unroll
    for (int p = 0; p < 2; ++p) {
      int idx = p * 256 + t;
      int r = idx >> 2, o = (idx & 3) * 8;
      *(u16x8*)&As[r][o] = *(const u16x8*)&A[(size_t)(m0 + r) * Kd + k0 + o];
      *(u16x8*)&Bs[r][o] = *(const u16x8*)&Bt[(size_t)(n0 + r) * Kd + k0 + o];
    }
    __syncthreads();
    bf16x8 af[4], bfr[4];
#pragma unroll
    for (int i = 0; i < 4; ++i) {
      af[i]  = ldb8(&As[wr * 64 + i * 16 + l16][lg * 8]);
      bfr[i] = ldb8(&Bs[wc * 64 + i * 16 + l16][lg * 8]);
    }
#pragma unroll
    for (int i = 0; i < 4; ++i)
#pragma unroll
      for (int j = 0; j < 4; ++j)
        acc[i][j] = __builtin_amdgcn_mfma_f32_16x16x32_bf16(af[i], bfr[j], acc[i][j], 0, 0, 0);
  }

  if (MODE == 1) {
#pragma unroll
    for (int i = 0; i < 4; ++i)
#pragma unroll
      for (int j = 0; j < 4; ++j)
#pragma unroll
        for (int r = 0; r < 4; ++r) {
          int m = m0 + wr * 64 + i * 16 + lg * 4 + r;
          int n = n0 + wc * 64 + j * 16 + l16;
          Cf[(size_t)m * N + n] = acc[i][j][r];
        }
  } else {
    int head = n0 >> 7;
#pragma unroll
    for (int i = 0; i < 4; ++i)
#pragma unroll
      for (int j = 0; j < 4; ++j)
#pragma unroll
        for (int r = 0; r < 4; ++r) {
          int m = m0 + wr * 64 + i * 16 + lg * 4 + r;
          int d = wc * 64 + j * 16 + l16;
          int b = m >> 11, s = m & (S_ - 1);
          u16 val = f2b(acc[i][j][r]);
          if (head < NH_) {
            Qb[(((size_t)b * NH_ + head) * S_ + s) * HD_ + d] = val;
          } else if (head < NH_ + NKV_) {
            Kb[(((size_t)b * NKV_ + (head - NH_)) * S_ + s) * HD_ + d] = val;
          } else {
            Vb[(((size_t)b * NKV_ + (head - NH_ - NKV_)) * HD_ + d) * S_ + s] = val;
          }
        }
  }
}

// ---------- kernel 4: RoPE in-place on [rows][128] bf16, one wave per row ----------
__global__ __launch_bounds__(256) void k_rope(u16* __restrict__ buf, const int* __restrict__ pos,
                                              const float* __restrict__ ct, const float* __restrict__ st,
                                              int H, int rows) {
  int wave = threadIdx.x >> 6, lane = threadIdx.x & 63;
  int row = blockIdx.x * 4 + wave;
  if (row >= rows) return;
  int s = row & (S_ - 1);
  int b = row / (H * S_);
  int p = pos[b * S_ + s];
  size_t base = (size_t)row * HD_;
  float x1 = b2f(buf[base + lane]);
  float x2 = b2f(buf[base + 64 + lane]);
  float c  = ct[(size_t)p * HD_ + lane];
  float sn = st[(size_t)p * HD_ + lane];
  buf[base + lane]      = f2b(x1 * c - x2 * sn);
  buf[base + 64 + lane] = f2b(x2 * c + x1 * sn);
}

// ---------- kernel 5: causal GQA flash attention (v2) ----------
// Pairing: block handles q-tiles pid and 31-pid (uniform ~33 kv-tiles of work).
// KVBLK=64 staged in XOR-swizzled LDS shared by 4 waves; swapped QK^T
// (mfma(K,Q)) puts the whole key range in-lane for one q row -> cheap softmax.
// LDS layout (40960 B total = 4 blocks/CU):
//   Ks [64 key][128 k]  bf16, row phys byte = row*256 + (off ^ ((row&7)<<4))
//   Vs [128 d][64 key]  bf16, row phys byte = row*128 + (off ^ ((row&7)<<4))
//   Ps [4 wave][16 q][64 key] bf16, same per-row XOR swizzle
__global__ __launch_bounds__(256, 4) void k_attn(const u16* __restrict__ Q,
                                                 const u16* __restrict__ K,
                                                 const u16* __restrict__ Vt,
                                                 u16* __restrict__ Ob) {
  __shared__ __align__(16) char smem[40960];
  const int VS_OFF = 16384, PS_OFF = 32768;

  int bid = blockIdx.x;
  int pid = bid & 15;
  int h   = (bid >> 4) & 31;
  int b   = bid >> 9;
  int kvh = h >> 2;
  int tid = threadIdx.x;
  int wave = tid >> 6, lane = tid & 63;
  int lg = lane >> 4, l16 = lane & 15;
  int lsw = (l16 & 7) << 4;            // per-row swizzle constant for frag reads

  const u16* Qp = Q  + (((size_t)b * NH_  + h)   * S_) * HD_;
  const u16* Kp = K  + (((size_t)b * NKV_ + kvh) * S_) * HD_;
  const u16* Vp = Vt + (((size_t)b * NKV_ + kvh) * HD_) * S_;

  for (int pass = 0; pass < 2; ++pass) {
    int qt = pass ? (31 - pid) : pid;
    int q0 = qt * 64 + wave * 16;      // this wave's 16 q rows
    int qg = q0 + l16;                 // lane's q row (swapped orientation)

    bf16x8 qf[4];
#pragma unroll
    for (int c = 0; c < 4; ++c)
      qf[c] = ldb8(&Qp[(size_t)qg * HD_ + c * 32 + lg * 8]);

    f32x4 oacc[8] = {};
    float mrun = -1e30f, lrun = 0.f;

    int nt = qt + 1;
    for (int tI = 0; tI < nt; ++tI) {
      int kb = tI * 64;
      __syncthreads();
      // ---- stage K tile: 64 rows x 256B ----
#pragma unroll
      for (int i = 0; i < 4; ++i) {
        int ci = i * 256 + tid;
        int r = ci >> 4, ch = ci & 15;
        u16x8 v = *(const u16x8*)&Kp[(size_t)(kb + r) * HD_ + ch * 8];
        *(u16x8*)(smem + r * 256 + ((ch * 16) ^ ((r & 7) << 4))) = v;
      }
      // ---- stage V tile (transposed layout): 128 rows x 128B ----
#pragma unroll
      for (int i = 0; i < 4; ++i) {
        int ci = i * 256 + tid;
        int r = ci >> 3, ch = ci & 7;
        u16x8 v = *(const u16x8*)&Vp[(size_t)r * S_ + kb + ch * 8];
        *(u16x8*)(smem + VS_OFF + r * 128 + ((ch * 16) ^ ((r & 7) << 4))) = v;
      }
      __syncthreads();

      // ---- QK^T swapped: sc[n] reg r @ lane(lg,l16) = S[key=n*16+lg*4+r][q=l16]
      f32x4 sc[4] = {};
#pragma unroll
      for (int c = 0; c < 4; ++c) {
#pragma unroll
        for (int n = 0; n < 4; ++n) {
          bf16x8 kf = ldb8b(smem + (n * 16 + l16) * 256 + ((c * 64 + lg * 16) ^ lsw));
          sc[n] = __builtin_amdgcn_mfma_f32_16x16x32_bf16(kf, qf[c], sc[n], 0, 0, 0);
        }
      }

      // ---- mask (diag tile only) + online softmax, keys in-lane ----
      bool diag = (tI == qt);
      float mx = -1e30f;
#pragma unroll
      for (int n = 0; n < 4; ++n)
#pragma unroll
        for (int r = 0; r < 4; ++r) {
          float v = sc[n][r];
          int key = kb + n * 16 + lg * 4 + r;
          if (diag && key > qg) v = -1e30f;
          sc[n][r] = v;
          mx = fmaxf(mx, v);
        }
      mx = fmaxf(mx, __shfl_xor(mx, 16));
      mx = fmaxf(mx, __shfl_xor(mx, 32));
      float mnew = fmaxf(mrun, mx * SCALE_);
      float alpha = __expf(mrun - mnew);
      float ps = 0.f;
#pragma unroll
      for (int n = 0; n < 4; ++n) {
        u16x4 pk;
#pragma unroll
        for (int r = 0; r < 4; ++r) {
          float p = __expf(fmaf(sc[n][r], SCALE_, -mnew));
          ps += p;
          pk[r] = f2b(p);
        }
        *(u16x4*)(smem + PS_OFF + wave * 2048 + l16 * 128 + ((n * 32 + lg * 8) ^ lsw)) = pk;
      }
      ps += __shfl_xor(ps, 16);
      ps += __shfl_xor(ps, 32);
      lrun = lrun * alpha + ps;
      mrun = mnew;

      // broadcast alpha (indexed by q=l16) to PV orientation (q=lg*4+r)
      float ar[4];
#pragma unroll
      for (int r = 0; r < 4; ++r) ar[r] = __shfl(alpha, lg * 4 + r);
#pragma unroll
      for (int ns = 0; ns < 8; ++ns)
#pragma unroll
        for (int r = 0; r < 4; ++r) oacc[ns][r] *= ar[r];

      // ---- PV: O[q][d] += P[q][k] V[k][d] ----
#pragma unroll
      for (int ck = 0; ck < 2; ++ck) {
        bf16x8 pa = ldb8b(smem + PS_OFF + wave * 2048 + l16 * 128 + ((ck * 64 + lg * 16) ^ lsw));
#pragma unroll
        for (int ns = 0; ns < 8; ++ns) {
          bf16x8 vf = ldb8b(smem + VS_OFF + (ns * 16 + l16) * 128 + ((ck * 64 + lg * 16) ^ lsw));
          oacc[ns] = __builtin_amdgcn_mfma_f32_16x16x32_bf16(pa, vf, oacc[ns], 0, 0, 0);
        }
      }
    }

    // ---- epilogue: normalize and store ----
    float lr[4];
#pragma unroll
    for (int r = 0; r < 4; ++r) lr[r] = 1.0f / __shfl(lrun, lg * 4 + r);
#pragma unroll
    for (int ns = 0; ns < 8; ++ns)
#pragma unroll
      for (int r = 0; r < 4; ++r) {
        int q = q0 + lg * 4 + r;
        Ob[((size_t)(b * S_) + q) * (NH_ * HD_) + h * HD_ + ns * 16 + l16] =
            f2b(oacc[ns][r] * lr[r]);
      }
  }
}

// ---------- launch ----------
extern "C" void kernel_launch(void* const* d_in, const int* in_sizes, int n_in,
                              void* d_out, int out_size, void* d_ws, size_t ws_size,
                              hipStream_t stream) {
  const float* hs  = (const float*)d_in[0];
  const int*   pos = (const int*)d_in[1];
  const float* ct  = (const float*)d_in[2];
  const float* st  = (const float*)d_in[3];
  const float* Wq  = (const float*)d_in[4];
  const float* Wk  = (const float*)d_in[5];
  const float* Wv  = (const float*)d_in[6];
  const float* Wo  = (const float*)d_in[7];
  float* out = (float*)d_out;

  char* w = (char*)d_ws;
  u16* Xb    = (u16*)(w);                       // [4096][4096]
  u16* WqkvT = (u16*)(w + 33554432ull);         // [6144][4096]
  u16* WoT   = (u16*)(w + 83886080ull);         // [4096][4096]
  u16* Qb    = (u16*)(w + 117440512ull);        // [2][32][2048][128]
  u16* Kb    = (u16*)(w + 150994944ull);        // [2][8][2048][128]
  u16* Vb    = (u16*)(w + 159383552ull);        // [2][8][128][2048]
  u16* Attb  = (u16*)(w + 167772160ull);        // [4096][4096]

  k_convx<<<16384, 256, 0, stream>>>(hs, Xb, 4194304);
  k_convT<<<dim3(64, 64), 256, 0, stream>>>(Wq, WqkvT, 4096, 4096);
  k_convT<<<dim3(64, 16), 256, 0, stream>>>(Wk, WqkvT + (size_t)4096 * 4096, 1024, 4096);
  k_convT<<<dim3(64, 16), 256, 0, stream>>>(Wv, WqkvT + (size_t)5120 * 4096, 1024, 4096);
  k_convT<<<dim3(64, 64), 256, 0, stream>>>(Wo, WoT, 4096, 4096);
  k_gemm<0><<<dim3(48, 32), 256, 0, stream>>>(Xb, WqkvT, nullptr, Qb, Kb, Vb, 4096, NTOT_, 4096);
  k_rope<<<32768, 256, 0, stream>>>(Qb, pos, ct, st, NH_, B_ * NH_ * S_);
  k_rope<<<8192, 256, 0, stream>>>(Kb, pos, ct, st, NKV_, B_ * NKV_ * S_);
  k_attn<<<1024, 256, 0, stream>>>(Qb, Kb, Vb, Attb);
  k_gemm<1><<<dim3(32, 32), 256, 0, stream>>>(Attb, WoT, out, nullptr, nullptr, nullptr, 4096, 4096, 4096);
}

// Round 3
// 715.380 us; speedup vs baseline: 2.0204x; 1.0229x over previous
//
#include <hip/hip_runtime.h>
#include <stdint.h>

typedef unsigned short u16;
typedef __bf16 bf16x8 __attribute__((ext_vector_type(8)));
typedef unsigned short u16x8 __attribute__((ext_vector_type(8)));
typedef unsigned short u16x4 __attribute__((ext_vector_type(4)));
typedef float f32x4 __attribute__((ext_vector_type(4)));

#define B_ 2
#define S_ 2048
#define HID_ 4096
#define NH_ 32
#define NKV_ 8
#define HD_ 128
#define NTOT_ 6144  // NH*HD + 2*NKV*HD
#define SCALE_ 0.08838834764831845f

// async global->LDS, 16B per lane, wave-uniform LDS base + lane*16 linear dest
#define GLD16(gp, lp)                                                     \
  __builtin_amdgcn_global_load_lds(                                       \
      (__attribute__((address_space(1))) void*)(gp),                      \
      (__attribute__((address_space(3))) void*)(lp), 16, 0, 0)

// ---------- bf16 helpers ----------
__device__ __forceinline__ u16 f2b(float f) {
  union { float f; uint32_t u; } v; v.f = f;
  uint32_t u = v.u;
  u = u + 0x7fffu + ((u >> 16) & 1u);   // round-to-nearest-even
  return (u16)(u >> 16);
}
__device__ __forceinline__ float b2f(u16 s) {
  union { uint32_t u; float f; } v; v.u = ((uint32_t)s) << 16;
  return v.f;
}
__device__ __forceinline__ bf16x8 ldb8(const u16* p) {
  u16x8 u = *(const u16x8*)p;
  return __builtin_bit_cast(bf16x8, u);
}
__device__ __forceinline__ bf16x8 ldb8b(const char* p) {
  u16x8 u = *(const u16x8*)p;
  return __builtin_bit_cast(bf16x8, u);
}

// ---------- kernel 1: f32 -> bf16 (vectorized) ----------
__global__ __launch_bounds__(256) void k_convx(const float* __restrict__ src,
                                               u16* __restrict__ dst, int n4) {
  int i = blockIdx.x * 256 + threadIdx.x;
  if (i >= n4) return;
  const float4 v = ((const float4*)src)[i];
  u16x4 o = { f2b(v.x), f2b(v.y), f2b(v.z), f2b(v.w) };
  *(u16x4*)(dst + (size_t)i * 4) = o;
}

// ---------- kernel 2: transpose-convert W f32 [Kd][N] -> bf16 [N][Kd] ----------
__global__ __launch_bounds__(256) void k_convT(const float* __restrict__ src,
                                               u16* __restrict__ dst, int N, int Kd) {
  __shared__ u16 tile[64][65];
  int k0 = blockIdx.x * 64, n0 = blockIdx.y * 64;
  int t = threadIdx.x;
  int rr = t >> 4;          // 0..15
  int cc = (t & 15) * 4;    // 0..60
#pragma unroll
  for (int p = 0; p < 4; ++p) {
    int r = p * 16 + rr;
    float4 v = *(const float4*)&src[(size_t)(k0 + r) * N + n0 + cc];
    tile[cc + 0][r] = f2b(v.x);
    tile[cc + 1][r] = f2b(v.y);
    tile[cc + 2][r] = f2b(v.z);
    tile[cc + 3][r] = f2b(v.w);
  }
  __syncthreads();
#pragma unroll
  for (int p = 0; p < 4; ++p) {
    int n = p * 16 + rr;
    u16x4 o = { tile[n][cc], tile[n][cc + 1], tile[n][cc + 2], tile[n][cc + 3] };
    *(u16x4*)&dst[(size_t)(n0 + n) * Kd + k0 + cc] = o;
  }
}

// ---------- kernel 3: bf16 GEMM, 128x128 tile, 4 waves, 16x16x32 MFMA ----------
// m97 structure: global_load_lds width-16 staging, 2-barrier K-loop.
// A: [M][Kd] bf16 row-major. Bt: [N][Kd] bf16 (B transposed).
// MODE 0: QKV epilogue (scatter to Q[b,h,s,d], K[b,kv,s,d], V^T[b,kv,d,s], bf16)
// MODE 1: f32 C output [M][N]
template <int MODE>
__global__ __launch_bounds__(256) void k_gemm(const u16* __restrict__ A,
                                              const u16* __restrict__ Bt,
                                              float* __restrict__ Cf,
                                              u16* __restrict__ Qb,
                                              u16* __restrict__ Kb,
                                              u16* __restrict__ Vb,
                                              int M, int N, int Kd) {
  __shared__ __align__(16) u16 As[128][32];
  __shared__ __align__(16) u16 Bs[128][32];
  int m0 = blockIdx.y * 128, n0 = blockIdx.x * 128;
  int t = threadIdx.x, lane = t & 63, wave = t >> 6;
  int wr = wave >> 1, wc = wave & 1;
  int lg = lane >> 4, l16 = lane & 15;
  f32x4 acc[4][4] = {};

  // per-lane global source (row = wave*32 + lane>>2, 16B chunk = lane&3)
  const u16* Ap = A  + (size_t)(m0 + wave * 32 + (lane >> 2)) * Kd + (lane & 3) * 8;
  const u16* Bp = Bt + (size_t)(n0 + wave * 32 + (lane >> 2)) * Kd + (lane & 3) * 8;
  // wave-uniform LDS dest bases (16 rows x 64B = 1024B per instruction)
  u16* AsW = &As[wave * 32][0];
  u16* BsW = &Bs[wave * 32][0];

  for (int k0 = 0; k0 < Kd; k0 += 32) {
    __syncthreads();                     // prev compute done before overwrite
    GLD16(Ap,           AsW);
    GLD16(Ap + 16 * Kd, AsW + 16 * 32);
    GLD16(Bp,           BsW);
    GLD16(Bp + 16 * Kd, BsW + 16 * 32);
    Ap += 32; Bp += 32;
    __syncthreads();                     // vmcnt(0) drain: tile ready
    bf16x8 af[4], bfr[4];
#pragma unroll
    for (int i = 0; i < 4; ++i) {
      af[i]  = ldb8(&As[wr * 64 + i * 16 + l16][lg * 8]);
      bfr[i] = ldb8(&Bs[wc * 64 + i * 16 + l16][lg * 8]);
    }
#pragma unroll
    for (int i = 0; i < 4; ++i)
#pragma unroll
      for (int j = 0; j < 4; ++j)
        acc[i][j] = __builtin_amdgcn_mfma_f32_16x16x32_bf16(af[i], bfr[j], acc[i][j], 0, 0, 0);
  }

  if (MODE == 1) {
#pragma unroll
    for (int i = 0; i < 4; ++i)
#pragma unroll
      for (int j = 0; j < 4; ++j)
#pragma unroll
        for (int r = 0; r < 4; ++r) {
          int m = m0 + wr * 64 + i * 16 + lg * 4 + r;
          int n = n0 + wc * 64 + j * 16 + l16;
          Cf[(size_t)m * N + n] = acc[i][j][r];
        }
  } else {
    int head = n0 >> 7;
#pragma unroll
    for (int i = 0; i < 4; ++i)
#pragma unroll
      for (int j = 0; j < 4; ++j)
#pragma unroll
        for (int r = 0; r < 4; ++r) {
          int m = m0 + wr * 64 + i * 16 + lg * 4 + r;
          int d = wc * 64 + j * 16 + l16;
          int b = m >> 11, s = m & (S_ - 1);
          u16 val = f2b(acc[i][j][r]);
          if (head < NH_) {
            Qb[(((size_t)b * NH_ + head) * S_ + s) * HD_ + d] = val;
          } else if (head < NH_ + NKV_) {
            Kb[(((size_t)b * NKV_ + (head - NH_)) * S_ + s) * HD_ + d] = val;
          } else {
            Vb[(((size_t)b * NKV_ + (head - NH_ - NKV_)) * HD_ + d) * S_ + s] = val;
          }
        }
  }
}

// ---------- kernel 4: RoPE in-place on [rows][128] bf16, one wave per row ----------
__global__ __launch_bounds__(256) void k_rope(u16* __restrict__ buf, const int* __restrict__ pos,
                                              const float* __restrict__ ct, const float* __restrict__ st,
                                              int H, int rows) {
  int wave = threadIdx.x >> 6, lane = threadIdx.x & 63;
  int row = blockIdx.x * 4 + wave;
  if (row >= rows) return;
  int s = row & (S_ - 1);
  int b = row / (H * S_);
  int p = pos[b * S_ + s];
  size_t base = (size_t)row * HD_;
  float x1 = b2f(buf[base + lane]);
  float x2 = b2f(buf[base + 64 + lane]);
  float c  = ct[(size_t)p * HD_ + lane];
  float sn = st[(size_t)p * HD_ + lane];
  buf[base + lane]      = f2b(x1 * c - x2 * sn);
  buf[base + 64 + lane] = f2b(x2 * c + x1 * sn);
}

// ---------- kernel 5: causal GQA flash attention (v2) ----------
__global__ __launch_bounds__(256, 4) void k_attn(const u16* __restrict__ Q,
                                                 const u16* __restrict__ K,
                                                 const u16* __restrict__ Vt,
                                                 u16* __restrict__ Ob) {
  __shared__ __align__(16) char smem[40960];
  const int VS_OFF = 16384, PS_OFF = 32768;

  int bid = blockIdx.x;
  int pid = bid & 15;
  int h   = (bid >> 4) & 31;
  int b   = bid >> 9;
  int kvh = h >> 2;
  int tid = threadIdx.x;
  int wave = tid >> 6, lane = tid & 63;
  int lg = lane >> 4, l16 = lane & 15;
  int lsw = (l16 & 7) << 4;

  const u16* Qp = Q  + (((size_t)b * NH_  + h)   * S_) * HD_;
  const u16* Kp = K  + (((size_t)b * NKV_ + kvh) * S_) * HD_;
  const u16* Vp = Vt + (((size_t)b * NKV_ + kvh) * HD_) * S_;

  for (int pass = 0; pass < 2; ++pass) {
    int qt = pass ? (31 - pid) : pid;
    int q0 = qt * 64 + wave * 16;
    int qg = q0 + l16;

    bf16x8 qf[4];
#pragma unroll
    for (int c = 0; c < 4; ++c)
      qf[c] = ldb8(&Qp[(size_t)qg * HD_ + c * 32 + lg * 8]);

    f32x4 oacc[8] = {};
    float mrun = -1e30f, lrun = 0.f;

    int nt = qt + 1;
    for (int tI = 0; tI < nt; ++tI) {
      int kb = tI * 64;
      __syncthreads();
#pragma unroll
      for (int i = 0; i < 4; ++i) {
        int ci = i * 256 + tid;
        int r = ci >> 4, ch = ci & 15;
        u16x8 v = *(const u16x8*)&Kp[(size_t)(kb + r) * HD_ + ch * 8];
        *(u16x8*)(smem + r * 256 + ((ch * 16) ^ ((r & 7) << 4))) = v;
      }
#pragma unroll
      for (int i = 0; i < 4; ++i) {
        int ci = i * 256 + tid;
        int r = ci >> 3, ch = ci & 7;
        u16x8 v = *(const u16x8*)&Vp[(size_t)r * S_ + kb + ch * 8];
        *(u16x8*)(smem + VS_OFF + r * 128 + ((ch * 16) ^ ((r & 7) << 4))) = v;
      }
      __syncthreads();

      f32x4 sc[4] = {};
#pragma unroll
      for (int c = 0; c < 4; ++c) {
#pragma unroll
        for (int n = 0; n < 4; ++n) {
          bf16x8 kf = ldb8b(smem + (n * 16 + l16) * 256 + ((c * 64 + lg * 16) ^ lsw));
          sc[n] = __builtin_amdgcn_mfma_f32_16x16x32_bf16(kf, qf[c], sc[n], 0, 0, 0);
        }
      }

      bool diag = (tI == qt);
      float mx = -1e30f;
#pragma unroll
      for (int n = 0; n < 4; ++n)
#pragma unroll
        for (int r = 0; r < 4; ++r) {
          float v = sc[n][r];
          int key = kb + n * 16 + lg * 4 + r;
          if (diag && key > qg) v = -1e30f;
          sc[n][r] = v;
          mx = fmaxf(mx, v);
        }
      mx = fmaxf(mx, __shfl_xor(mx, 16));
      mx = fmaxf(mx, __shfl_xor(mx, 32));
      float mnew = fmaxf(mrun, mx * SCALE_);
      float alpha = __expf(mrun - mnew);
      float ps = 0.f;
#pragma unroll
      for (int n = 0; n < 4; ++n) {
        u16x4 pk;
#pragma unroll
        for (int r = 0; r < 4; ++r) {
          float p = __expf(fmaf(sc[n][r], SCALE_, -mnew));
          ps += p;
          pk[r] = f2b(p);
        }
        *(u16x4*)(smem + PS_OFF + wave * 2048 + l16 * 128 + ((n * 32 + lg * 8) ^ lsw)) = pk;
      }
      ps += __shfl_xor(ps, 16);
      ps += __shfl_xor(ps, 32);
      lrun = lrun * alpha + ps;
      mrun = mnew;

      float ar[4];
#pragma unroll
      for (int r = 0; r < 4; ++r) ar[r] = __shfl(alpha, lg * 4 + r);
#pragma unroll
      for (int ns = 0; ns < 8; ++ns)
#pragma unroll
        for (int r = 0; r < 4; ++r) oacc[ns][r] *= ar[r];

#pragma unroll
      for (int ck = 0; ck < 2; ++ck) {
        bf16x8 pa = ldb8b(smem + PS_OFF + wave * 2048 + l16 * 128 + ((ck * 64 + lg * 16) ^ lsw));
#pragma unroll
        for (int ns = 0; ns < 8; ++ns) {
          bf16x8 vf = ldb8b(smem + VS_OFF + (ns * 16 + l16) * 128 + ((ck * 64 + lg * 16) ^ lsw));
          oacc[ns] = __builtin_amdgcn_mfma_f32_16x16x32_bf16(pa, vf, oacc[ns], 0, 0, 0);
        }
      }
    }

    float lr[4];
#pragma unroll
    for (int r = 0; r < 4; ++r) lr[r] = 1.0f / __shfl(lrun, lg * 4 + r);
#pragma unroll
    for (int ns = 0; ns < 8; ++ns)
#pragma unroll
      for (int r = 0; r < 4; ++r) {
        int q = q0 + lg * 4 + r;
        Ob[((size_t)(b * S_) + q) * (NH_ * HD_) + h * HD_ + ns * 16 + l16] =
            f2b(oacc[ns][r] * lr[r]);
      }
  }
}

// ---------- launch ----------
extern "C" void kernel_launch(void* const* d_in, const int* in_sizes, int n_in,
                              void* d_out, int out_size, void* d_ws, size_t ws_size,
                              hipStream_t stream) {
  const float* hs  = (const float*)d_in[0];
  const int*   pos = (const int*)d_in[1];
  const float* ct  = (const float*)d_in[2];
  const float* st  = (const float*)d_in[3];
  const float* Wq  = (const float*)d_in[4];
  const float* Wk  = (const float*)d_in[5];
  const float* Wv  = (const float*)d_in[6];
  const float* Wo  = (const float*)d_in[7];
  float* out = (float*)d_out;

  char* w = (char*)d_ws;
  u16* Xb    = (u16*)(w);                       // [4096][4096]
  u16* WqkvT = (u16*)(w + 33554432ull);         // [6144][4096]
  u16* WoT   = (u16*)(w + 83886080ull);         // [4096][4096]
  u16* Qb    = (u16*)(w + 117440512ull);        // [2][32][2048][128]
  u16* Kb    = (u16*)(w + 150994944ull);        // [2][8][2048][128]
  u16* Vb    = (u16*)(w + 159383552ull);        // [2][8][128][2048]
  u16* Attb  = (u16*)(w + 167772160ull);        // [4096][4096]

  k_convx<<<16384, 256, 0, stream>>>(hs, Xb, 4194304);
  k_convT<<<dim3(64, 64), 256, 0, stream>>>(Wq, WqkvT, 4096, 4096);
  k_convT<<<dim3(64, 16), 256, 0, stream>>>(Wk, WqkvT + (size_t)4096 * 4096, 1024, 4096);
  k_convT<<<dim3(64, 16), 256, 0, stream>>>(Wv, WqkvT + (size_t)5120 * 4096, 1024, 4096);
  k_convT<<<dim3(64, 64), 256, 0, stream>>>(Wo, WoT, 4096, 4096);
  k_gemm<0><<<dim3(48, 32), 256, 0, stream>>>(Xb, WqkvT, nullptr, Qb, Kb, Vb, 4096, NTOT_, 4096);
  k_rope<<<32768, 256, 0, stream>>>(Qb, pos, ct, st, NH_, B_ * NH_ * S_);
  k_rope<<<8192, 256, 0, stream>>>(Kb, pos, ct, st, NKV_, B_ * NKV_ * S_);
  k_attn<<<1024, 256, 0, stream>>>(Qb, Kb, Vb, Attb);
  k_gemm<1><<<dim3(32, 32), 256, 0, stream>>>(Attb, WoT, out, nullptr, nullptr, nullptr, 4096, 4096, 4096);
}